// Round 7
// baseline (131.748 us; speedup 1.0000x reference)
//
#include <hip/hip_runtime.h>
#include <stdint.h>

#define IN_DIM 4096
#define ITERS 4   // compile-time trip count: nvec == ITERS * grid * block (asserted in launch)

typedef float f32x4 __attribute__((ext_vector_type(4)));

__global__ __launch_bounds__(256) void snn_step_kernel(
    const int*   __restrict__ x,    // (IN,1) int32 binary spikes
    const f32x4* __restrict__ W,    // (OUT,IN) f32, 4 elems per vec
    const f32x4* __restrict__ T,    // trace
    const f32x4* __restrict__ D,    // delay (small non-negative ints as f32)
    const float* __restrict__ dtp,
    const float* __restrict__ taup,
    const float* __restrict__ alp,
    f32x4* __restrict__ O0,         // weight * spike_out
    f32x4* __restrict__ O1)         // trace_new
{
    const float k  = (*dtp) / (*taup);  // dt/tau
    const float al = *alp;

    const int tid    = blockIdx.x * blockDim.x + threadIdx.x;
    const int stride = gridDim.x * blockDim.x;

    // stride*4 floats is a multiple of IN_DIM -> x slice is loop-invariant.
    const int col = (tid * 4) & (IN_DIM - 1);
    const int4 xv = *(const int4*)(x + col);
    const float ax0 = al * (float)xv.x;
    const float ax1 = al * (float)xv.y;
    const float ax2 = al * (float)xv.z;
    const float ax3 = al * (float)xv.w;

    // Issue ALL loads first (12 nt-loads in flight per thread), then compute,
    // then store. Non-temporal: bypass LLC retention — the harness's 1 GiB
    // inter-replay fill churns the cache anyway; cached reads cost more than
    // they save (round 6: nt = -9.5%).
    f32x4 wv[ITERS], tv[ITERS], dv[ITERS];
    int vi[ITERS];
    #pragma unroll
    for (int it = 0; it < ITERS; ++it) {
        const int v = tid + it * stride;
        vi[it] = v;
        wv[it] = __builtin_nontemporal_load(W + v);
        tv[it] = __builtin_nontemporal_load(T + v);
        dv[it] = __builtin_nontemporal_load(D + v);
    }

    #pragma unroll
    for (int it = 0; it < ITERS; ++it) {
        f32x4 o, n;
        // trace_new = trace + k*(-trace + alpha*x)  (reference op order)
        n.x = tv[it].x + k * (ax0 - tv[it].x);
        n.y = tv[it].y + k * (ax1 - tv[it].y);
        n.z = tv[it].z + k * (ax2 - tv[it].z);
        n.w = tv[it].w + k * (ax3 - tv[it].w);
        // spike = ((d>0 ? d-1 : d) == 1); d is an exact small int
        o.x = ((dv[it].x > 0.0f ? dv[it].x - 1.0f : dv[it].x) == 1.0f) ? wv[it].x : 0.0f;
        o.y = ((dv[it].y > 0.0f ? dv[it].y - 1.0f : dv[it].y) == 1.0f) ? wv[it].y : 0.0f;
        o.z = ((dv[it].z > 0.0f ? dv[it].z - 1.0f : dv[it].z) == 1.0f) ? wv[it].z : 0.0f;
        o.w = ((dv[it].w > 0.0f ? dv[it].w - 1.0f : dv[it].w) == 1.0f) ? wv[it].w : 0.0f;
        __builtin_nontemporal_store(o, O0 + vi[it]);
        __builtin_nontemporal_store(n, O1 + vi[it]);
    }
}

// Fallback for shapes where nvec != ITERS*stride (not taken for the bench shape).
__global__ __launch_bounds__(256) void snn_step_kernel_generic(
    const int* __restrict__ x, const f32x4* __restrict__ W,
    const f32x4* __restrict__ T, const f32x4* __restrict__ D,
    const float* __restrict__ dtp, const float* __restrict__ taup,
    const float* __restrict__ alp,
    f32x4* __restrict__ O0, f32x4* __restrict__ O1, int nvec)
{
    const float k  = (*dtp) / (*taup);
    const float al = *alp;
    const int stride = gridDim.x * blockDim.x;
    for (int v = blockIdx.x * blockDim.x + threadIdx.x; v < nvec; v += stride) {
        const int c = (v * 4) & (IN_DIM - 1);
        const int4 xt = *(const int4*)(x + c);
        const f32x4 wv = W[v], tv = T[v], dv = D[v];
        f32x4 o, n;
        n.x = tv.x + k * (al * (float)xt.x - tv.x);
        n.y = tv.y + k * (al * (float)xt.y - tv.y);
        n.z = tv.z + k * (al * (float)xt.z - tv.z);
        n.w = tv.w + k * (al * (float)xt.w - tv.w);
        o.x = ((dv.x > 0.0f ? dv.x - 1.0f : dv.x) == 1.0f) ? wv.x : 0.0f;
        o.y = ((dv.y > 0.0f ? dv.y - 1.0f : dv.y) == 1.0f) ? wv.y : 0.0f;
        o.z = ((dv.z > 0.0f ? dv.z - 1.0f : dv.z) == 1.0f) ? wv.z : 0.0f;
        o.w = ((dv.w > 0.0f ? dv.w - 1.0f : dv.w) == 1.0f) ? wv.w : 0.0f;
        O0[v] = o;
        O1[v] = n;
    }
}

extern "C" void kernel_launch(void* const* d_in, const int* in_sizes, int n_in,
                              void* d_out, int out_size, void* d_ws, size_t ws_size,
                              hipStream_t stream) {
    // setup_inputs order: x, weight, trace, delay, delay_init(UNUSED), dt, tau_t, alpha_t
    const int*   x  = (const int*)d_in[0];
    const f32x4* W  = (const f32x4*)d_in[1];
    const f32x4* T  = (const f32x4*)d_in[2];
    const f32x4* D  = (const f32x4*)d_in[3];
    // d_in[4] = delay_init: dead in the reference (delay_new is deleted) — never read.
    const float* dtp  = (const float*)d_in[5];
    const float* taup = (const float*)d_in[6];
    const float* alp  = (const float*)d_in[7];

    const int n_elems = in_sizes[1];        // OUT*IN = 33,554,432
    const int nvec    = n_elems / 4;

    f32x4* O0 = (f32x4*)d_out;
    f32x4* O1 = (f32x4*)((float*)d_out + n_elems);

    const int block  = 256;
    const int grid   = 8192;                // 4x oversubscription for backfill
    const int stride = grid * block;

    if (nvec == ITERS * stride && (stride * 4) % IN_DIM == 0) {
        snn_step_kernel<<<grid, block, 0, stream>>>(x, W, T, D, dtp, taup, alp, O0, O1);
    } else {
        snn_step_kernel_generic<<<2048, block, 0, stream>>>(x, W, T, D, dtp, taup, alp,
                                                            O0, O1, nvec);
    }
}

// Round 8
// 120.637 us; speedup vs baseline: 1.0921x; 1.0921x over previous
//
#include <hip/hip_runtime.h>
#include <stdint.h>

#define IN_DIM 4096

typedef float f32x4 __attribute__((ext_vector_type(4)));

__global__ __launch_bounds__(256) void snn_step_kernel(
    const int*   __restrict__ x,    // (IN,1) int32 binary spikes
    const f32x4* __restrict__ W,    // (OUT,IN) f32, 4 elems per vec
    const f32x4* __restrict__ T,    // trace
    const f32x4* __restrict__ D,    // delay (small non-negative ints as f32)
    const float* __restrict__ dtp,
    const float* __restrict__ taup,
    const float* __restrict__ alp,
    f32x4* __restrict__ O0,         // weight * spike_out
    f32x4* __restrict__ O1,         // trace_new
    int iters, int nvec)
{
    const float k  = (*dtp) / (*taup);  // dt/tau
    const float al = *alp;

    const int tid    = blockIdx.x * blockDim.x + threadIdx.x;
    const int stride = gridDim.x * blockDim.x;

    // stride*4 floats is a multiple of IN_DIM -> x slice is loop-invariant.
    const int col = (tid * 4) & (IN_DIM - 1);
    const int4 xv = *(const int4*)(x + col);
    const float ax0 = al * (float)xv.x;
    const float ax1 = al * (float)xv.y;
    const float ax2 = al * (float)xv.z;
    const float ax3 = al * (float)xv.w;

    // Round-6 configuration — best known (121.1 us, 5.54 TB/s on 3R+2W):
    // 2048 blocks x 16 iters, per-iteration issue, nt on ALL five streams.
    // (Round 7's 12-deep load batching + 8192 blocks regressed 9% — reverted.)
    #pragma unroll 4
    for (int it = 0; it < iters; ++it) {
        const int v = tid + it * stride;
        const f32x4 wv = __builtin_nontemporal_load(W + v);
        const f32x4 tv = __builtin_nontemporal_load(T + v);
        const f32x4 dv = __builtin_nontemporal_load(D + v);

        f32x4 o, n;
        // trace_new = trace + k*(-trace + alpha*x)  (reference op order)
        n.x = tv.x + k * (ax0 - tv.x);
        n.y = tv.y + k * (ax1 - tv.y);
        n.z = tv.z + k * (ax2 - tv.z);
        n.w = tv.w + k * (ax3 - tv.w);
        // spike = ((d>0 ? d-1 : d) == 1); d is an exact small int
        o.x = ((dv.x > 0.0f ? dv.x - 1.0f : dv.x) == 1.0f) ? wv.x : 0.0f;
        o.y = ((dv.y > 0.0f ? dv.y - 1.0f : dv.y) == 1.0f) ? wv.y : 0.0f;
        o.z = ((dv.z > 0.0f ? dv.z - 1.0f : dv.z) == 1.0f) ? wv.z : 0.0f;
        o.w = ((dv.w > 0.0f ? dv.w - 1.0f : dv.w) == 1.0f) ? wv.w : 0.0f;

        __builtin_nontemporal_store(o, O0 + v);
        __builtin_nontemporal_store(n, O1 + v);
    }

    // Tail (not taken for the bench shape: nvec == iters * stride)
    const int v = tid + iters * stride;
    if (v < nvec) {
        const int c2 = (v * 4) & (IN_DIM - 1);
        const int4 xt = *(const int4*)(x + c2);
        const f32x4 wv = W[v];
        const f32x4 tv = T[v];
        const f32x4 dv = D[v];
        f32x4 o, n;
        n.x = tv.x + k * (al * (float)xt.x - tv.x);
        n.y = tv.y + k * (al * (float)xt.y - tv.y);
        n.z = tv.z + k * (al * (float)xt.z - tv.z);
        n.w = tv.w + k * (al * (float)xt.w - tv.w);
        o.x = ((dv.x > 0.0f ? dv.x - 1.0f : dv.x) == 1.0f) ? wv.x : 0.0f;
        o.y = ((dv.y > 0.0f ? dv.y - 1.0f : dv.y) == 1.0f) ? wv.y : 0.0f;
        o.z = ((dv.z > 0.0f ? dv.z - 1.0f : dv.z) == 1.0f) ? wv.z : 0.0f;
        o.w = ((dv.w > 0.0f ? dv.w - 1.0f : dv.w) == 1.0f) ? wv.w : 0.0f;
        O0[v] = o;
        O1[v] = n;
    }
}

extern "C" void kernel_launch(void* const* d_in, const int* in_sizes, int n_in,
                              void* d_out, int out_size, void* d_ws, size_t ws_size,
                              hipStream_t stream) {
    // setup_inputs order: x, weight, trace, delay, delay_init(UNUSED), dt, tau_t, alpha_t
    const int*   x  = (const int*)d_in[0];
    const f32x4* W  = (const f32x4*)d_in[1];
    const f32x4* T  = (const f32x4*)d_in[2];
    const f32x4* D  = (const f32x4*)d_in[3];
    // d_in[4] = delay_init: dead in the reference (delay_new is deleted) — never read.
    const float* dtp  = (const float*)d_in[5];
    const float* taup = (const float*)d_in[6];
    const float* alp  = (const float*)d_in[7];

    const int n_elems = in_sizes[1];        // OUT*IN = 33,554,432
    const int nvec    = n_elems / 4;

    f32x4* O0 = (f32x4*)d_out;
    f32x4* O1 = (f32x4*)((float*)d_out + n_elems);

    const int block  = 256;
    const int grid   = 2048;
    const int stride = grid * block;
    const int iters  = nvec / stride;       // 16 for the bench shape
    snn_step_kernel<<<grid, block, 0, stream>>>(x, W, T, D, dtp, taup, alp,
                                                O0, O1, iters, nvec);
}